// Round 6
// baseline (209.032 us; speedup 1.0000x reference)
//
#include <hip/hip_runtime.h>

typedef short short8 __attribute__((ext_vector_type(8)));
typedef float floatx4 __attribute__((ext_vector_type(4)));
typedef unsigned short u16;
typedef unsigned long long u64;

#define Tn 2048
#define Kdim 1024
// 1/sqrt(64) * log2(e): folded into Q so flash softmax runs in exp2 domain
#define QSCALE 0.18033688011112042f
#define FIXEDMAX 20.0f   // exp2-domain logits are ~+-5; 20 is a safe fixed max

__device__ inline u16 f2bf(float x) {
    union { float f; unsigned u; } c; c.f = x;
    unsigned u = c.u;
    u += 0x7fffu + ((u >> 16) & 1u);   // round-to-nearest-even
    return (u16)(u >> 16);
}
__device__ inline float bf2f(u16 h) {
    union { unsigned u; float f; } c; c.u = ((unsigned)h) << 16;
    return c.f;
}
__device__ inline floatx4 mfma16(short8 a, short8 b, floatx4 c) {
    return __builtin_amdgcn_mfma_f32_16x16x32_bf16(a, b, c, 0, 0, 0);
}
__device__ inline void async16(const void* g, void* l) {
    __builtin_amdgcn_global_load_lds((const __attribute__((address_space(1))) void*)g,
                                     (__attribute__((address_space(3))) void*)l, 16, 0, 0);
}

// ---------------- fused f32 -> bf16 convert (x, Wq, Wk, Wv, Wo) ----------------
__global__ __launch_bounds__(256) void cvt_all_k(
    const float* __restrict__ x, const float* __restrict__ wq, const float* __restrict__ wk,
    const float* __restrict__ wv, const float* __restrict__ wo, u16* __restrict__ dst)
{
    int i = blockIdx.x * 256 + threadIdx.x;   // float4 index
    const float* s; int off;
    if (i < 1048576) { s = x; off = i; }
    else {
        int j = i - 1048576; int seg = j >> 18; off = j & 262143;
        s = (seg == 0) ? wq : (seg == 1) ? wk : (seg == 2) ? wv : wo;
    }
    float4 v = ((const float4*)s)[off];
    u64 pk = (u64)f2bf(v.x) | ((u64)f2bf(v.y) << 16) | ((u64)f2bf(v.z) << 32) | ((u64)f2bf(v.w) << 48);
    ((u64*)dst)[i] = pk;
}

// ---------------- QKV GEMM: C = A(M,K) @ W(N,K)^T + bias, 128M x 64N tile, BK=64 ----------------
__global__ __launch_bounds__(256, 5) void gemm_qkv_k(
    const u16* __restrict__ A,
    const u16* __restrict__ W0, const u16* __restrict__ W1, const u16* __restrict__ W2,
    const float* __restrict__ b0, const float* __restrict__ b1, const float* __restrict__ b2,
    u16* o0, u16* o1, u16* o2,
    const float2* __restrict__ rope)
{
    int z = blockIdx.z;
    const u16* W = (z == 0) ? W0 : (z == 1 ? W1 : W2);
    const float* bias = (z == 0) ? b0 : (z == 1 ? b1 : b2);
    u16* outp = (z == 0) ? o0 : (z == 1 ? o1 : o2);

    __shared__ __align__(16) char lds[24576];   // A [0,16K): 128 rows x 128B; W [16K,24K): 64 rows x 128B
    int tid = threadIdx.x;
    int w = tid >> 6, lane = tid & 63, quad = lane >> 4, l15 = lane & 15;
    int m0 = blockIdx.y * 128, n0 = blockIdx.x * 64;
    int wm = w * 32;

    floatx4 acc[2][4];
    floatx4 vzero = {0.f, 0.f, 0.f, 0.f};
#pragma unroll
    for (int i = 0; i < 2; ++i)
#pragma unroll
        for (int j = 0; j < 4; ++j) acc[i][j] = vzero;

    for (int k0 = 0; k0 < Kdim; k0 += 64) {
#pragma unroll
        for (int j = 0; j < 4; ++j) {
            int f = j * 256 + tid, r = f >> 3, c = (f & 7) ^ (r & 7);
            async16(A + (size_t)(m0 + r) * Kdim + k0 + c * 8, lds + j * 4096 + w * 1024);
        }
#pragma unroll
        for (int j = 0; j < 2; ++j) {
            int f = j * 256 + tid, r = f >> 3, c = (f & 7) ^ (r & 7);
            async16(W + (size_t)(n0 + r) * Kdim + k0 + c * 8, lds + 16384 + j * 4096 + w * 1024);
        }
        __syncthreads();
        short8 af[2][2];
#pragma unroll
        for (int mt = 0; mt < 2; ++mt) {
            int ra = wm + mt * 16 + l15;
            const char* pa = lds + ra * 128;
#pragma unroll
            for (int ks = 0; ks < 2; ++ks)
                af[mt][ks] = *(const short8*)(pa + (((ks * 4 + quad) ^ (ra & 7)) << 4));
        }
#pragma unroll
        for (int ks = 0; ks < 2; ++ks)
#pragma unroll
            for (int nt = 0; nt < 4; ++nt) {
                int rb = nt * 16 + l15;
                short8 bf = *(const short8*)(lds + 16384 + rb * 128 + (((ks * 4 + quad) ^ (rb & 7)) << 4));
                acc[0][nt] = mfma16(af[0][ks], bf, acc[0][nt]);
                acc[1][nt] = mfma16(af[1][ks], bf, acc[1][nt]);
            }
        __syncthreads();
    }

    int mbase = m0 + wm;
    if (z <= 1) {
        float osc = (z == 0) ? QSCALE : 1.0f;
#pragma unroll
        for (int nt = 0; nt < 4; ++nt) {
            int col = n0 + nt * 16 + l15;
            float bv = bias[col];
            int p = (col & 63) >> 1;
#pragma unroll
            for (int mt = 0; mt < 2; ++mt) {
                floatx4 a = acc[mt][nt];
#pragma unroll
                for (int r = 0; r < 4; ++r) {
                    int row = mbase + mt * 16 + quad * 4 + r;
                    float v = a[r] + bv;
                    float ov = __shfl_xor(v, 1, 64);
                    float2 cs = rope[(row & (Tn - 1)) * 32 + p];
                    float res = (cs.x * v + ((lane & 1) ? cs.y * ov : -cs.y * ov)) * osc;
                    float pres = __shfl_xor(res, 1, 64);
                    if (!(lane & 1)) {
                        unsigned pk = (unsigned)f2bf(res) | ((unsigned)f2bf(pres) << 16);
                        *(unsigned*)(outp + (size_t)row * 1024 + col) = pk;
                    }
                }
            }
        }
    } else {
#pragma unroll
        for (int nt = 0; nt < 4; ++nt) {
            int col = n0 + nt * 16 + l15;
            float bv = bias[col];
#pragma unroll
            for (int mt = 0; mt < 2; ++mt) {
                floatx4 a = acc[mt][nt];
                int row0 = mbase + mt * 16 + quad * 4;
                int bb = row0 >> 11, t0 = row0 & (Tn - 1);
                u64 pk = (u64)f2bf(a[0] + bv) | ((u64)f2bf(a[1] + bv) << 16)
                       | ((u64)f2bf(a[2] + bv) << 32) | ((u64)f2bf(a[3] + bv) << 48);
                *(u64*)(outp + (size_t)(bb * 1024 + col) * Tn + t0) = pk;
            }
        }
    }
}

// ---------------- O-projection GEMM: out = Y(M,K) @ Wo(N,K)^T, f32 out, 64x64 tile ----------------
__global__ __launch_bounds__(256, 6) void gemm_o_k(
    const u16* __restrict__ A, const u16* __restrict__ W, float* __restrict__ out)
{
    __shared__ __align__(16) char lds[16384];
    int tid = threadIdx.x;
    int w = tid >> 6, lane = tid & 63, quad = lane >> 4, l15 = lane & 15;
    int m0 = blockIdx.y * 64, n0 = blockIdx.x * 64;
    int wm = (w >> 1) * 32, wn = (w & 1) * 32;

    floatx4 acc[2][2];
    floatx4 vzero = {0.f, 0.f, 0.f, 0.f};
#pragma unroll
    for (int i = 0; i < 2; ++i)
#pragma unroll
        for (int j = 0; j < 2; ++j) acc[i][j] = vzero;

    for (int k0 = 0; k0 < Kdim; k0 += 64) {
#pragma unroll
        for (int j = 0; j < 2; ++j) {
            int f = j * 256 + tid, r = f >> 3, c = (f & 7) ^ (r & 7);
            async16(A + (size_t)(m0 + r) * Kdim + k0 + c * 8, lds + j * 4096 + w * 1024);
            async16(W + (size_t)(n0 + r) * Kdim + k0 + c * 8, lds + 8192 + j * 4096 + w * 1024);
        }
        __syncthreads();
        short8 af[2][2];
#pragma unroll
        for (int mt = 0; mt < 2; ++mt) {
            int ra = wm + mt * 16 + l15;
            const char* pa = lds + ra * 128;
#pragma unroll
            for (int ks = 0; ks < 2; ++ks)
                af[mt][ks] = *(const short8*)(pa + (((ks * 4 + quad) ^ (ra & 7)) << 4));
        }
#pragma unroll
        for (int ks = 0; ks < 2; ++ks)
#pragma unroll
            for (int nt = 0; nt < 2; ++nt) {
                int rb = wn + nt * 16 + l15;
                short8 bf = *(const short8*)(lds + 8192 + rb * 128 + (((ks * 4 + quad) ^ (rb & 7)) << 4));
                acc[0][nt] = mfma16(af[0][ks], bf, acc[0][nt]);
                acc[1][nt] = mfma16(af[1][ks], bf, acc[1][nt]);
            }
        __syncthreads();
    }

#pragma unroll
    for (int nt = 0; nt < 2; ++nt) {
        int col = n0 + wn + nt * 16 + l15;
#pragma unroll
        for (int mt = 0; mt < 2; ++mt) {
            floatx4 a = acc[mt][nt];
#pragma unroll
            for (int r = 0; r < 4; ++r) {
                int row = m0 + wm + mt * 16 + quad * 4 + r;
                out[(size_t)row * 1024 + col] = a[r];
            }
        }
    }
}

// ---------------- Vmean (for degenerate fully-masked rows) ----------------
__global__ __launch_bounds__(64) void vmean_k(const u16* __restrict__ Vt, float* __restrict__ vmean) {
    int row = blockIdx.x;
    int lane = threadIdx.x;
    const u16* p = Vt + (size_t)row * Tn;
    float s = 0.f;
    for (int i = lane * 8; i < Tn; i += 512) {
        short8 v = *(const short8*)(p + i);
#pragma unroll
        for (int j = 0; j < 8; ++j) s += bf2f((u16)v[j]);
    }
#pragma unroll
    for (int off = 1; off < 64; off <<= 1) s += __shfl_xor(s, off, 64);
    if (lane == 0) vmean[row] = s * (1.f / 2048.f);
}

// ---------------- Flash attention (fixed-max exp2 softmax, K-split long q-tiles) ----------------
// Fixed-max => partial (O, l) over any key sub-range combine by ADDITION.
// bid < 1024: qt >= 16 split in 2 key-halves -> bf16 partial O + f32 partial l to scratch.
// bid >= 1024: qt <= 15 whole -> writes Yb directly.
// Mask + (-FIXEDMAX) folded into QK accumulator init; causal select only on kt == qt.
__global__ __launch_bounds__(256) void flash_k(
    const u16* __restrict__ Qb, const u16* __restrict__ Kb, const u16* __restrict__ Vt,
    const int* __restrict__ masks, const float* __restrict__ vmean, u16* __restrict__ Yb,
    u16* __restrict__ oP, float* __restrict__ lS)
{
    int bid = blockIdx.x;
    int qt, bh, half, kt0, kt1, split;
    if (bid < 1024) {
        qt = 31 - (bid >> 6);
        bh = (bid & 7) * 4 + ((bid >> 3) & 3);
        half = (bid >> 5) & 1;
        int h0 = (qt + 1) >> 1;
        kt0 = half ? h0 : 0;
        kt1 = half ? (qt + 1) : h0;
        split = 1;
    } else {
        int j = bid - 1024;
        qt = 15 - (j >> 5);
        bh = (j & 7) * 4 + ((j >> 3) & 3);
        half = 0; kt0 = 0; kt1 = qt + 1; split = 0;
    }
    int b = bh >> 4, h = bh & 15;
    int tid = threadIdx.x, w = tid >> 6, lane = tid & 63, quad = lane >> 4, l15 = lane & 15;
    int sc = (lane & 7) ^ (lane >> 3);   // staging chunk so that LDS slot = chunk ^ (row&7)

    __shared__ __align__(16) u16 ldsK[2][64 * 64];   // row=key, 8x16B slots, swizzled (16KB)
    __shared__ __align__(16) u16 ldsV[2][64 * 64];   // row=d,   8x16B slots, swizzled (16KB)
    __shared__ __align__(16) u16 ldsP[4][16 * 64];   // per wave, 16 rows x 128B, swizzled (8KB)

    // mask ballots in registers: lane j holds ballot of key-tile j
    unsigned blo = 0, bhi = 0;
    for (int j = kt0; j < kt1; ++j) {
        u64 mk = __ballot(masks[b * Tn + j * 64 + lane] != 0);
        if (lane == j) { blo = (unsigned)mk; bhi = (unsigned)(mk >> 32); }
    }

    auto stage = [&](int bb, int k0) {
#pragma unroll
        for (int j = 0; j < 2; ++j) {
            int row = j * 32 + w * 8 + (lane >> 3);
            const u16* gk = Kb + (size_t)(b * Tn + k0 + row) * 1024 + h * 64 + sc * 8;
            async16(gk, (char*)&ldsK[bb][0] + (j * 32 + w * 8) * 128);
            const u16* gv = Vt + (size_t)(b * 1024 + h * 64 + row) * Tn + k0 + sc * 8;
            async16(gv, (char*)&ldsV[bb][0] + (j * 32 + w * 8) * 128);
        }
    };
    floatx4 vzero = {0.f, 0.f, 0.f, 0.f};

    int q0 = qt * 64 + w * 16;
    short8 qf[2];
    {
        const u16* qp = Qb + (size_t)(b * Tn + q0 + l15) * 1024 + h * 64 + quad * 8;
        qf[0] = *(const short8*)qp;
        qf[1] = *(const short8*)(qp + 32);
    }
    floatx4 o[4];
    float lsum[4] = {0.f, 0.f, 0.f, 0.f};
#pragma unroll
    for (int i = 0; i < 4; ++i) o[i] = vzero;

    stage(0, kt0 * 64);
    for (int kt = kt0; kt < kt1; ++kt) {
        int k0 = kt * 64;
        int bb = (kt - kt0) & 1;
        __syncthreads();   // tile kt staged; all waves done with other buffer

        short8 kf[4][2], vf[4][2];
#pragma unroll
        for (int f = 0; f < 4; ++f) {
            int key = f * 16 + l15;
            const char* kbase = (const char*)&ldsK[bb][0] + key * 128;
            const char* vbase = (const char*)&ldsV[bb][0] + key * 128;
#pragma unroll
            for (int ks = 0; ks < 2; ++ks) {
                int slot = ((quad + ks * 4) ^ (key & 7)) << 4;
                kf[f][ks] = *(const short8*)(kbase + slot);
                vf[f][ks] = *(const short8*)(vbase + slot);
            }
        }
        if (kt + 1 < kt1) stage(bb ^ 1, k0 + 64);   // prefetch flies during compute

        // mask + fixed-max folded into accumulator init: C = masked ? -1e10 : -FIXEDMAX
        unsigned mlo = __shfl(blo, kt, 64), mhi = __shfl(bhi, kt, 64);
        floatx4 s[4];
        {
            float m0i = ((mlo >> l15) & 1) ? -1.0e10f : -FIXEDMAX;
            float m1i = ((mlo >> (l15 + 16)) & 1) ? -1.0e10f : -FIXEDMAX;
            float m2i = ((mhi >> l15) & 1) ? -1.0e10f : -FIXEDMAX;
            float m3i = ((mhi >> (l15 + 16)) & 1) ? -1.0e10f : -FIXEDMAX;
            s[0] = (floatx4){m0i, m0i, m0i, m0i};
            s[1] = (floatx4){m1i, m1i, m1i, m1i};
            s[2] = (floatx4){m2i, m2i, m2i, m2i};
            s[3] = (floatx4){m3i, m3i, m3i, m3i};
        }
#pragma unroll
        for (int f = 0; f < 4; ++f) {
            s[f] = mfma16(qf[0], kf[f][0], s[f]);
            s[f] = mfma16(qf[1], kf[f][1], s[f]);
        }

        if (kt == qt) {
            // diagonal tile: per-element causal select
#pragma unroll
            for (int r = 0; r < 4; ++r) {
                int lim = q0 + quad * 4 + r - k0;
                float psum = 0.f;
#pragma unroll
                for (int f = 0; f < 4; ++f) {
                    float v = (16 * f + l15 > lim) ? -1.0e10f : s[f][r];
                    float p = __builtin_amdgcn_exp2f(v);
                    psum += p;
                    unsigned u = __float_as_uint(p) + 0x8000u;
                    int row = quad * 4 + r, key = f * 16 + l15;
                    *((u16*)((char*)&ldsP[w][0] + row * 128 +
                             ((((key >> 3) ^ (row & 7))) << 4) + (key & 7) * 2)) = (u16)(u >> 16);
                }
                lsum[r] += psum;
            }
        } else {
#pragma unroll
            for (int r = 0; r < 4; ++r) {
                float psum = 0.f;
#pragma unroll
                for (int f = 0; f < 4; ++f) {
                    float p = __builtin_amdgcn_exp2f(s[f][r]);
                    psum += p;
                    unsigned u = __float_as_uint(p) + 0x8000u;
                    int row = quad * 4 + r, key = f * 16 + l15;
                    *((u16*)((char*)&ldsP[w][0] + row * 128 +
                             ((((key >> 3) ^ (row & 7))) << 4) + (key & 7) * 2)) = (u16)(u >> 16);
                }
                lsum[r] += psum;
            }
        }
        __asm__ volatile("s_waitcnt lgkmcnt(0)" ::: "memory");   // wave-local P roundtrip
        short8 pf0 = *(const short8*)((const char*)&ldsP[w][0] + l15 * 128 + ((quad ^ (l15 & 7)) << 4));
        short8 pf1 = *(const short8*)((const char*)&ldsP[w][0] + l15 * 128 + (((quad + 4) ^ (l15 & 7)) << 4));
#pragma unroll
        for (int nb = 0; nb < 4; ++nb) {
            o[nb] = mfma16(pf0, vf[nb][0], o[nb]);
            o[nb] = mfma16(pf1, vf[nb][1], o[nb]);
        }
    }

    if (!split) {
#pragma unroll
        for (int r = 0; r < 4; ++r) {
            int qq = q0 + quad * 4 + r;
            float l = lsum[r];
#pragma unroll
            for (int off = 1; off < 16; off <<= 1) l += __shfl_xor(l, off, 64);
            bool degen = (l == 0.f);   // fully-masked row -> reference attends uniformly to ALL keys
            float linv = 1.0f / l;
#pragma unroll
            for (int nb = 0; nb < 4; ++nb) {
                int d = nb * 16 + l15;
                float val = degen ? vmean[b * 1024 + h * 64 + d] : o[nb][r] * linv;
                float pv = __shfl_xor(val, 1, 64);
                if (!(lane & 1)) {
                    unsigned pk = (unsigned)f2bf(val) | ((unsigned)f2bf(pv) << 16);
                    *(unsigned*)(Yb + (size_t)(b * Tn + qq) * 1024 + h * 64 + d) = pk;
                }
            }
        }
    } else {
        int sq = (qt - 16) * 32 + bh;
        u16* ob = oP + (size_t)(half * 512 + sq) * 4096;
        float* lb = lS + (size_t)(half * 512 + sq) * 64;
#pragma unroll
        for (int r = 0; r < 4; ++r) {
            int q = w * 16 + quad * 4 + r;
            float l = lsum[r];
#pragma unroll
            for (int off = 1; off < 16; off <<= 1) l += __shfl_xor(l, off, 64);
            if (l15 == 0) lb[q] = l;
#pragma unroll
            for (int nb = 0; nb < 4; ++nb) {
                int d = nb * 16 + l15;
                float val = o[nb][r];
                float pv = __shfl_xor(val, 1, 64);
                if (!(lane & 1)) {
                    unsigned pk = (unsigned)f2bf(val) | ((unsigned)f2bf(pv) << 16);
                    *(unsigned*)(ob + q * 64 + d) = pk;
                }
            }
        }
    }
}

// ---------------- finalize split q-tiles: sum halves, normalize, write Yb ----------------
__global__ __launch_bounds__(256) void fin_k(
    const u16* __restrict__ oP, const float* __restrict__ lS,
    const float* __restrict__ vmean, u16* __restrict__ Yb)
{
    int blk = blockIdx.x;            // 2048 = 512 sq x 4 q-groups
    int sq = blk >> 2, qg = blk & 3;
    int qt = 16 + (sq >> 5), bh = sq & 31, b = bh >> 4, h = bh & 15;
    int tid = threadIdx.x;
    int q = qg * 16 + (tid >> 4);
    int d0 = (tid & 15) * 4;
    u64 ua = *(const u64*)(oP + (size_t)sq * 4096 + q * 64 + d0);
    u64 ub = *(const u64*)(oP + (size_t)(512 + sq) * 4096 + q * 64 + d0);
    float l = lS[sq * 64 + q] + lS[(512 + sq) * 64 + q];
    bool degen = (l == 0.f);
    float linv = 1.0f / l;
    u64 outp = 0;
#pragma unroll
    for (int i = 0; i < 4; ++i) {
        float va = bf2f((u16)(ua >> (16 * i))), vb = bf2f((u16)(ub >> (16 * i)));
        float val = degen ? vmean[b * 1024 + h * 64 + d0 + i] : (va + vb) * linv;
        outp |= (u64)f2bf(val) << (16 * i);
    }
    int qrow = qt * 64 + q;
    *(u64*)(Yb + (size_t)(b * Tn + qrow) * 1024 + h * 64 + d0) = outp;
}

extern "C" void kernel_launch(void* const* d_in, const int* in_sizes, int n_in,
                              void* d_out, int out_size, void* d_ws, size_t ws_size,
                              hipStream_t stream) {
    const float* x  = (const float*)d_in[0];
    const int* masks = (const int*)d_in[1];
    const float* Wq = (const float*)d_in[2];
    const float* bq = (const float*)d_in[3];
    const float* Wk = (const float*)d_in[4];
    const float* bk = (const float*)d_in[5];
    const float* Wv = (const float*)d_in[6];
    const float* bv = (const float*)d_in[7];
    const float* Wo = (const float*)d_in[8];
    const float2* rope = (const float2*)d_in[9];
    float* out = (float*)d_out;

    char* ws = (char*)d_ws;
    u16* xb   = (u16*)(ws);               // [0,8MB)  dead after gemm_qkv -> reused as oP
    u16* Wqb  = (u16*)(ws + (8  << 20));  // [8,10MB) dead after gemm_qkv -> reused as lS
    u16* Wkb  = (u16*)(ws + (10 << 20));
    u16* Wvb  = (u16*)(ws + (12 << 20));
    u16* Wob  = (u16*)(ws + (14 << 20));
    u16* Qb   = (u16*)(ws + (16 << 20));
    u16* Kb2  = (u16*)(ws + (24 << 20));
    u16* Vt   = (u16*)(ws + (32 << 20));
    u16* Yb   = (u16*)(ws + (40 << 20));
    float* vm = (float*)(ws + (48 << 20));
    u16* oP   = (u16*)(ws);               // 2 x 512 x 4096 bf16 = 8MB (overlays xb)
    float* lS = (float*)(ws + (8 << 20)); // 2 x 512 x 64 f32 = 256KB (overlays Wqb)

    // fused f32 -> bf16 (x, Wq, Wk, Wv, Wo -> contiguous ws region)
    cvt_all_k<<<8192, 256, 0, stream>>>(x, Wq, Wk, Wv, Wo, xb);

    // fused QKV projection (+bias, rope on Q/K with QSCALE on Q, V transposed)
    gemm_qkv_k<<<dim3(16, 32, 3), 256, 0, stream>>>(xb, Wqb, Wkb, Wvb, bq, bk, bv,
                                                    Qb, Kb2, Vt, rope);
    // mean of V per (b,h,d) for degenerate fully-masked rows
    vmean_k<<<2048, 64, 0, stream>>>(Vt, vm);
    // flash attention (qt>=16 K-split into halves -> scratch; qt<=15 direct)
    flash_k<<<1536, 256, 0, stream>>>(Qb, Kb2, Vt, masks, vm, Yb, oP, lS);
    // combine split halves
    fin_k<<<2048, 256, 0, stream>>>(oP, lS, vm, Yb);
    // output projection -> f32 d_out
    gemm_o_k<<<dim3(16, 64), 256, 0, stream>>>(Yb, Wob, out);
}